// Round 2
// baseline (2652.560 us; speedup 1.0000x reference)
//
#include <hip/hip_runtime.h>
#include <hip/hip_bf16.h>

// ---------------- problem constants ----------------
#define BSZ 64
#define SEQ 2048
#define HD  256
#define ND  256
#define BS_TOK (BSZ*SEQ)          // 131072 tokens
#define NCAND 101
#define EPS 1e-5f

using bf16 = __hip_bfloat16;
typedef unsigned short u16;
typedef unsigned int   u32;
typedef __attribute__((ext_vector_type(8))) short short8v;   // 8 bf16 (4 VGPRs)
typedef __attribute__((ext_vector_type(4))) float f32x4;

__device__ __forceinline__ float clampf(float v, float c) { return fminf(fmaxf(v, -c), c); }

// fp32 -> (hi,lo) bf16 split: x ~= hi + lo exactly to ~2^-17 rel
__device__ __forceinline__ void split_bf(float x, u16& h, u16& l) {
  u32 u = __float_as_uint(x);
  h = (u16)(u >> 16);
  float d = x - __uint_as_float(u & 0xffff0000u);
  l = (u16)(__float_as_uint(d) >> 16);
}
__device__ __forceinline__ u32 pack_pair(float x) {
  u16 h, l; split_bf(x, h, l);
  return (u32)h | ((u32)l << 16);
}
__device__ __forceinline__ float unpack_pair(u32 p) {
  return __uint_as_float(p << 16) + __uint_as_float(p & 0xffff0000u);
}

// async 16B global->LDS (wave-uniform LDS base + lane*16)
__device__ __forceinline__ void async_copy16(const void* g, void* l) {
  __builtin_amdgcn_global_load_lds(
      (const __attribute__((address_space(1))) void*)g,
      (__attribute__((address_space(3))) void*)l, 16, 0, 0);
}

// virtual-k pair swizzle: element (row r, logical col c) stored as u32 at
//   row*ldau32 + (c&~31) + ((((c>>2)&7) ^ (r&7))<<2) + (c&3)
__device__ __forceinline__ int vswz(int c, int rb7) {
  return (c & ~31) + ((((c >> 2) & 7) ^ rb7) << 2) + (c & 3);
}

// ---------------- workspace layout ----------------
static constexpr size_t MiB = 1024*1024;
static constexpr size_t OFF_X    = 0;                         // Xf fp32 [BS_TOK,256]
static constexpr size_t OFF_PR   = 128*MiB;                   // fp32[1024]: abr[512] abi[512]
static constexpr size_t OFF_WB   = OFF_PR + 4096;             // u16[2097152] = 4 MiB virt planes
static constexpr size_t OFF_XLR  = OFF_WB + 4*MiB;
static constexpr size_t OFF_XLI  = OFF_XLR + 65536;
static constexpr size_t OFF_YL   = OFF_XLI + 65536;
static constexpr size_t OFF_XF   = OFF_YL  + 65536;
static constexpr size_t OFF_CH   = 136*MiB;                   // Hb pairs 2*CB MiB, Sb 4*CB MiB

// wb u16 offsets (virtual-K duplicated planes, k-major per output col)
static constexpr int WB_BB0H = 0,       WB_BB0L = 262144;     // [512][Kv=512]
static constexpr int WB_BB1H = 524288,  WB_BB1L = 786432;
static constexpr int WB_WSH  = 1048576, WB_WSL  = 1310720;    // [256][Kv=1024]
static constexpr int WB_W1H  = 1572864, WB_W1L  = 1703936;    // [256][Kv=512]
static constexpr int WB_W2H  = 1835008, WB_W2L  = 1966080;

// ---------------- param pack ----------------
__global__ __launch_bounds__(256) void pack_k(
    const float* __restrict__ lar, const float* __restrict__ aim, const float* __restrict__ lstep,
    const float* __restrict__ C0, const float* __restrict__ W1, const float* __restrict__ W2,
    const float* __restrict__ Bf,
    float* __restrict__ pr, u16* __restrict__ wb)
{
  int gid = blockIdx.x*256 + threadIdx.x;   // grid 256 -> 65536
  if (gid < 512) {
    int blk = gid >> 8;
    float step = expf(clampf(lstep[blk], 10.f));
    float ar = -expf(clampf(lar[gid], 20.f));
    float ai = aim[gid];
    float er = expf(fminf(ar*step, 0.f));
    pr[gid]       = er * cosf(ai*step);
    pr[512 + gid] = er * sinf(ai*step);
  }
  int r = gid >> 8, c = gid & 255;          // r = n (state)/out col, c = h (hidden)/k
  u16 h, l;
#pragma unroll
  for (int blk = 0; blk < 2; ++blk) {
    float step = expf(clampf(lstep[blk], 10.f));
    float ar = -expf(clampf(lar[blk*256 + c], 20.f));
    float ai = aim[blk*256 + c];
    float er  = expf(fminf(ar*step, 0.f));
    float abr = er * cosf(ai*step);
    float abi = er * sinf(ai*step);
    float den = ar*ar + ai*ai;
    float tr = abr - 1.f, ti = abi;
    float cr = (tr*ar + ti*ai) / den;
    float ci = (ti*ar - tr*ai) / den;
    float bv = Bf[blk*65536 + r*256 + c];
    u16* Bh = wb + (blk ? WB_BB1H : WB_BB0H);
    u16* Bl = wb + (blk ? WB_BB1L : WB_BB0L);
    split_bf(cr * bv, h, l);
    Bh[r*512 + 2*c] = h; Bh[r*512 + 2*c + 1] = h;
    Bl[r*512 + 2*c] = l; Bl[r*512 + 2*c + 1] = l;
    split_bf(ci * bv, h, l);
    Bh[(256+r)*512 + 2*c] = h; Bh[(256+r)*512 + 2*c + 1] = h;
    Bl[(256+r)*512 + 2*c] = l; Bl[(256+r)*512 + 2*c + 1] = l;
  }
  // Wstk virt: out col = h (r), k = [n | 256+n] -> Kv=1024
  split_bf( C0[(size_t)(r*256 + c)*2    ], h, l);
  wb[WB_WSH + r*1024 + 2*c] = h; wb[WB_WSH + r*1024 + 2*c + 1] = h;
  wb[WB_WSL + r*1024 + 2*c] = l; wb[WB_WSL + r*1024 + 2*c + 1] = l;
  split_bf(-C0[(size_t)(r*256 + c)*2 + 1], h, l);
  wb[WB_WSH + r*1024 + 512 + 2*c] = h; wb[WB_WSH + r*1024 + 512 + 2*c + 1] = h;
  wb[WB_WSL + r*1024 + 512 + 2*c] = l; wb[WB_WSL + r*1024 + 512 + 2*c + 1] = l;
  // W1T/W2T virt: out col = n (r), k = c
  split_bf(W1[c*256 + r], h, l);
  wb[WB_W1H + r*512 + 2*c] = h; wb[WB_W1H + r*512 + 2*c + 1] = h;
  wb[WB_W1L + r*512 + 2*c] = l; wb[WB_W1L + r*512 + 2*c + 1] = l;
  split_bf(W2[c*256 + r], h, l);
  wb[WB_W2H + r*512 + 2*c] = h; wb[WB_W2H + r*512 + 2*c + 1] = h;
  wb[WB_W2L + r*512 + 2*c] = l; wb[WB_W2L + r*512 + 2*c + 1] = l;
}

// ---------------- embedding + mask ----------------
__global__ __launch_bounds__(256) void embed_k(
    const int* __restrict__ seqs, const float* __restrict__ iemb,
    const float* __restrict__ pemb, float* __restrict__ Xf)
{
  int token = blockIdx.x; int h = threadIdx.x;
  int id = seqs[token];
  int pos = token & (SEQ-1);
  float v = 0.f;
  if (id != 0) v = iemb[(size_t)id*HD + h] + pemb[(size_t)pos*HD + h];
  Xf[(size_t)token*HD + h] = v;
}

// ---------------- LayerNorm (1 wave per row) -> swizzled (h,l) pair output ----------------
template<bool ADD_DU>
__global__ __launch_bounds__(256) void ln_rows(
    float* __restrict__ Xf, const float* __restrict__ g, const float* __restrict__ b,
    u32* __restrict__ OutP, const float* __restrict__ Dv)
{
  int w = threadIdx.x >> 6, lane = threadIdx.x & 63;
  size_t row = (size_t)blockIdx.x * 4 + w;
  float* xrow = Xf + row*HD;
  float4 xv = ((const float4*)xrow)[lane];
  float x[4] = {xv.x, xv.y, xv.z, xv.w};
  float s = 0.f, s2 = 0.f;
#pragma unroll
  for (int k = 0; k < 4; ++k) { s += x[k]; s2 += x[k]*x[k]; }
#pragma unroll
  for (int off = 32; off > 0; off >>= 1) { s += __shfl_xor(s, off, 64); s2 += __shfl_xor(s2, off, 64); }
  float m = s * (1.f/256.f);
  float var = fmaxf(s2 * (1.f/256.f) - m*m, 0.f);
  float rinv = rsqrtf(var + EPS);
  int c0 = lane*4;
  u32 pv[4];
  float nx[4];
#pragma unroll
  for (int k = 0; k < 4; ++k) {
    float u = (x[k] - m) * rinv * g[c0+k] + b[c0+k];
    pv[k] = pack_pair(u);
    if (ADD_DU) nx[k] = x[k] + Dv[c0+k] * u;
  }
  int rb7 = (int)(row & 7);
  size_t o = row*256 + ((lane >> 3) << 5) + ((((lane & 7) ^ rb7)) << 2);
  *(uint4*)(OutP + o) = make_uint4(pv[0], pv[1], pv[2], pv[3]);
  if (ADD_DU) ((float4*)xrow)[lane] = make_float4(nx[0], nx[1], nx[2], nx[3]);
}

// ---------------- virtual-K pair MFMA GEMM ----------------
// out[m,n] = sum_k A[m,k] * W[n,k]; A = swizzled (h,l) u32 pairs (virt-K = 2K),
// W = duplicated bf16 planes (wh,wh / wl,wl). Two MFMA passes = exact (h+l)(wh+wl).
// A staged to LDS with global_load_lds 16B (linear dest, pre-swizzled source layout).
// 128x128 tile, 4 waves 2x2 of 64x64. XCD-bijective block remap.
// EPI: 0 = Of[row*ldo+col] = v  (fp32, for scan)
//      2 = Op[row*ldo + vswz(col)] = pair(relu(v + bias[col]))
//      3 = Xf = (Xf + v + bias[col]) * mask(ids[row])
//      4 = Xf += v
template<int EPI, int CB_N>
__global__ __launch_bounds__(256) void mgemm(
    const u32* __restrict__ A, int ldau32,
    const u16* __restrict__ Bh, const u16* __restrict__ Bl, int Kv, int ldo,
    float* __restrict__ Xf, float* __restrict__ Of, u32* __restrict__ Op,
    const float* __restrict__ bias, const int* __restrict__ ids)
{
  __shared__ __align__(16) u16 As[128*64];
  const int tid  = threadIdx.x;
  const int lane = tid & 63, wid = tid >> 6;
  const int wr = wid >> 1, wc = wid & 1;
  const int l16 = lane & 15, lhi = lane >> 4;
  // XCD-bijective remap: all CB_N col-blocks of a row-panel -> same XCD
  int g = blockIdx.x;
  int x = g & 7, j = g >> 3;
  int cb = j % CB_N, rbk = j / CB_N;
  const int m0 = (rbk*8 + x) * 128;
  const int n0 = cb*128 + wc*64;
  f32x4 acc[4][4] = {};
  const u16* A16 = (const u16*)A;
  const size_t lda16 = (size_t)ldau32 * 2;

  for (int kbv = 0; kbv < Kv; kbv += 64) {
    __syncthreads();
    // stage 128 rows x 64 virt-u16 = 16 KiB, 16 wave-calls of 1 KiB
#pragma unroll
    for (int i = 0; i < 4; ++i) {
      int ch = (wid*4 + i)*64 + lane;               // 0..1023
      int rr = ch >> 3, grp = ch & 7;
      const u16* src = A16 + (size_t)(m0 + rr)*lda16 + kbv + grp*8;
      async_copy16(src, &As[(wid*4 + i)*512]);
    }
    __syncthreads();
#pragma unroll
    for (int kk = 0; kk < 64; kk += 32) {
      short8v af[4];
      const int c8r = (kk >> 3) + lhi;
#pragma unroll
      for (int rf = 0; rf < 4; ++rf) {
        int r = wr*64 + rf*16 + l16;
        int off = r*64 + ((c8r ^ (r & 7)) << 3);
        af[rf] = *(const short8v*)&As[off];
      }
#pragma unroll
      for (int nf = 0; nf < 4; ++nf) {
        size_t bo = (size_t)(n0 + nf*16 + l16)*Kv + kbv + kk + lhi*8;
        short8v bh = *(const short8v*)(Bh + bo);
        short8v bl = *(const short8v*)(Bl + bo);
#pragma unroll
        for (int rf = 0; rf < 4; ++rf) {
          f32x4 c = acc[rf][nf];
          c = __builtin_amdgcn_mfma_f32_16x16x32_bf16(af[rf], bh, c, 0, 0, 0);
          c = __builtin_amdgcn_mfma_f32_16x16x32_bf16(af[rf], bl, c, 0, 0, 0);
          acc[rf][nf] = c;
        }
      }
    }
  }
#pragma unroll
  for (int rf = 0; rf < 4; ++rf) {
#pragma unroll
    for (int jj = 0; jj < 4; ++jj) {
      int row = m0 + wr*64 + rf*16 + lhi*4 + jj;
      int rb7 = row & 7;
      int idv = 0;
      if (EPI == 3) idv = ids[row];
#pragma unroll
      for (int nf = 0; nf < 4; ++nf) {
        int col = n0 + nf*16 + l16;
        float v = acc[rf][nf][jj];
        if (EPI == 0) {
          Of[(size_t)row*ldo + col] = v;
        } else if (EPI == 2) {
          float t = fmaxf(v + bias[col], 0.f);
          Op[(size_t)row*ldo + vswz(col, rb7)] = pack_pair(t);
        } else if (EPI == 3) {
          size_t idx = (size_t)row*ldo + col;
          float t = Xf[idx] + v + bias[col];
          Xf[idx] = (idv != 0) ? t : 0.f;
        } else {
          size_t idx = (size_t)row*ldo + col;
          Xf[idx] = Xf[idx] + v;
        }
      }
    }
  }
}

// ---------------- diagonal complex scan ----------------
// STORE: reads fp32 [row,512] (exact), writes swizzled (h,l) pairs IN PLACE
// (each lane rewrites only the slots of its own column set -> race-free).
template<bool STORE>
__global__ __launch_bounds__(64) void scan_k(
    float* __restrict__ Sb,
    const float* __restrict__ arp, const float* __restrict__ aip,
    float* __restrict__ xlast_r, float* __restrict__ xlast_i)
{
  int lane = threadIdx.x;
  int b = blockIdx.x >> 2;                    // chunk-local batch
  int n = ((blockIdx.x & 3) << 6) | lane;
  float Ar = arp[n], Ai = aip[n];
  float xr = 0.f, xi = 0.f;
  float* sp = Sb + (size_t)b*SEQ*512 + n;
  u32*  qp = (u32*)Sb + (size_t)b*SEQ*512;
  int cr_base = (n & ~31) + (n & 3),        cr_g = (n >> 2) & 7;
  int ni = 256 + n;
  int ci_base = (ni & ~31) + (ni & 3),      ci_g = (ni >> 2) & 7;
  for (int t = 0; t < SEQ; ++t) {
    float sr = sp[0], si = sp[256];
    float nxr = Ar*xr - Ai*xi + sr;
    float nxi = Ar*xi + Ai*xr + si;
    xr = nxr; xi = nxi;
    if (STORE) {
      int rb = t & 7;
      qp[(size_t)t*512 + cr_base + ((cr_g ^ rb) << 2)] = pack_pair(xr);
      qp[(size_t)t*512 + ci_base + ((ci_g ^ rb) << 2)] = pack_pair(xi);
    }
    sp += 512;
  }
  if (!STORE) { xlast_r[b*ND + n] = xr; xlast_i[b*ND + n] = xi; }
}

// ---------------- block-1 last-position tail ----------------
__global__ __launch_bounds__(256) void ylast_k(
    const float* __restrict__ xr, const float* __restrict__ xi,
    const float* __restrict__ C1, const float* __restrict__ D1,
    const u32* __restrict__ U,                                  // chunk-local Hb pairs
    const float* __restrict__ Xf, int b0, float* __restrict__ ylr)
{
  int bl = blockIdx.x, h = threadIdx.x;
  __shared__ float sxr[256], sxi[256];
  sxr[h] = xr[bl*256 + h]; sxi[h] = xi[bl*256 + h];
  __syncthreads();
  float acc = 0.f;
  for (int n = 0; n < 256; ++n) {
    acc += C1[(size_t)(h*256 + n)*2] * sxr[n] - C1[(size_t)(h*256 + n)*2 + 1] * sxi[n];
  }
  size_t lrow = (size_t)bl*SEQ + SEQ - 1;     // last row; (row&7)==7
  u32 up = U[lrow*256 + vswz(h, 7)];
  float uval = unpack_pair(up);
  size_t gidx = ((size_t)(b0 + bl)*SEQ + SEQ - 1)*HD + h;
  ylr[(b0 + bl)*256 + h] = Xf[gidx] + acc + D1[h] * uval;
}

__device__ __forceinline__ float block_sum256(float v, volatile float* red) {
#pragma unroll
  for (int off = 32; off > 0; off >>= 1) v += __shfl_xor(v, off, 64);
  int w = threadIdx.x >> 6;
  __syncthreads();
  if ((threadIdx.x & 63) == 0) red[w] = v;
  __syncthreads();
  return red[0] + red[1] + red[2] + red[3];
}

__global__ __launch_bounds__(256) void tail_k(
    const float* __restrict__ ylr, const float* __restrict__ g1, const float* __restrict__ bb1,
    const float* __restrict__ W1p, const float* __restrict__ b1p,
    const float* __restrict__ W2p, const float* __restrict__ b2p,
    const float* __restrict__ fg, const float* __restrict__ fb,
    const int* __restrict__ seqs, float* __restrict__ xfin)
{
  __shared__ float sh[256];
  __shared__ float red[4];
  int b = blockIdx.x, h = threadIdx.x;
  float x = ylr[b*256 + h];
  float m = block_sum256(x, red) * (1.f/256.f);
  float d = x - m;
  float var = fmaxf(block_sum256(d*d, red) * (1.f/256.f), 0.f);
  float h2 = d * rsqrtf(var + EPS) * g1[h] + bb1[h];
  __syncthreads();
  sh[h] = h2;
  __syncthreads();
  float acc = 0.f;
  for (int k = 0; k < 256; ++k) acc += sh[k] * W1p[k*256 + h];
  float f = fmaxf(acc + b1p[h], 0.f);
  __syncthreads();
  sh[h] = f;
  __syncthreads();
  acc = 0.f;
  for (int k = 0; k < 256; ++k) acc += sh[k] * W2p[k*256 + h];
  float x2 = x + acc + b2p[h];
  if (seqs[b*SEQ + SEQ - 1] == 0) x2 = 0.f;
  float m2 = block_sum256(x2, red) * (1.f/256.f);
  float d2 = x2 - m2;
  float v2 = fmaxf(block_sum256(d2*d2, red) * (1.f/256.f), 0.f);
  xfin[b*256 + h] = d2 * rsqrtf(v2 + EPS) * fg[h] + fb[h];
}

// NOTE: reference output dtype is float32 -> d_out is float*.
__global__ __launch_bounds__(256) void logits_k(
    const float* __restrict__ xfin, const int* __restrict__ cand,
    const float* __restrict__ iemb, float* __restrict__ out)
{
  int gid = blockIdx.x*4 + (threadIdx.x >> 6);
  if (gid >= BSZ*NCAND) return;
  int lane = threadIdx.x & 63;
  int b = gid / NCAND;
  int id = cand[gid];
  const float* e  = iemb + (size_t)id*HD;
  const float* xv = xfin + b*256;
  float acc = 0.f;
#pragma unroll
  for (int k = 0; k < 4; ++k) acc += xv[lane*4 + k] * e[lane*4 + k];
#pragma unroll
  for (int off = 32; off > 0; off >>= 1) acc += __shfl_xor(acc, off, 64);
  if (lane == 0) out[gid] = acc;
}

// ---------------- launch ----------------
extern "C" void kernel_launch(void* const* d_in, const int* in_sizes, int n_in,
                              void* d_out, int out_size, void* d_ws, size_t ws_size,
                              hipStream_t stream)
{
  const int*   seqs  = (const int*)d_in[0];
  const int*   cand  = (const int*)d_in[1];
  const float* iemb  = (const float*)d_in[2];
  const float* pemb  = (const float*)d_in[3];
  const float* ln_g  = (const float*)d_in[4];
  const float* ln_b  = (const float*)d_in[5];
  const float* lar   = (const float*)d_in[6];
  const float* aim   = (const float*)d_in[7];
  const float* Bssm  = (const float*)d_in[8];
  const float* Cssm  = (const float*)d_in[9];
  const float* Dssm  = (const float*)d_in[10];
  const float* lstep = (const float*)d_in[11];
  const float* W1    = (const float*)d_in[12];
  const float* b1    = (const float*)d_in[13];
  const float* W2    = (const float*)d_in[14];
  const float* b2    = (const float*)d_in[15];
  const float* lnfg  = (const float*)d_in[16];
  const float* lnfb  = (const float*)d_in[17];

  char* ws = (char*)d_ws;
  float* Xf   = (float*)(ws + OFF_X);
  float* pr   = (float*)(ws + OFF_PR);
  u16*   wb   = (u16*)  (ws + OFF_WB);
  float* xlr  = (float*)(ws + OFF_XLR);
  float* xli  = (float*)(ws + OFF_XLI);
  float* ylr  = (float*)(ws + OFF_YL);
  float* xfin = (float*)(ws + OFF_XF);

  // chunk sizing: Hb pairs = 2*CB MiB, Sb = 4*CB MiB
  int CB = 64;
  while (CB > 1 && (OFF_CH + (size_t)6*CB*MiB) > ws_size) CB >>= 1;
  u32*   HbP = (u32*)(ws + OFF_CH);
  float* SbC = (float*)(ws + OFF_CH + (size_t)2*CB*MiB);

  pack_k<<<256, 256, 0, stream>>>(lar, aim, lstep, Cssm, W1, W2, Bssm, pr, wb);
  embed_k<<<BS_TOK, 256, 0, stream>>>(seqs, iemb, pemb, Xf);

  const int rows = CB*SEQ;
  const int rb   = rows / 128;
  for (int b0 = 0; b0 < BSZ; b0 += CB) {
    float* XfC = Xf + (size_t)b0*SEQ*HD;
    const int* seqC = seqs + (size_t)b0*SEQ;

    // ---- block 0: S4 ----
    ln_rows<true><<<rows/4, 256, 0, stream>>>(XfC, ln_g, ln_b, HbP, Dssm);
    mgemm<0,4><<<4*rb, 256, 0, stream>>>(HbP, 256, wb + WB_BB0H, wb + WB_BB0L, 512, 512,
                                         nullptr, SbC, nullptr, nullptr, nullptr);
    scan_k<true><<<CB*4, 64, 0, stream>>>(SbC, pr, pr+512, nullptr, nullptr);
    mgemm<4,2><<<2*rb, 256, 0, stream>>>((u32*)SbC, 512, wb + WB_WSH, wb + WB_WSL, 1024, 256,
                                         XfC, nullptr, nullptr, nullptr, nullptr);
    // ---- block 0: FFN ----
    ln_rows<false><<<rows/4, 256, 0, stream>>>(XfC, ln_g, ln_b, HbP, nullptr);
    mgemm<2,2><<<2*rb, 256, 0, stream>>>(HbP, 256, wb + WB_W1H, wb + WB_W1L, 512, 256,
                                         nullptr, nullptr, (u32*)SbC, b1, nullptr);
    mgemm<3,2><<<2*rb, 256, 0, stream>>>((u32*)SbC, 256, wb + WB_W2H, wb + WB_W2L, 512, 256,
                                         XfC, nullptr, nullptr, b2, seqC);
    // ---- block 1 (only last position needed downstream of the scan) ----
    ln_rows<false><<<rows/4, 256, 0, stream>>>(XfC, ln_g + 256, ln_b + 256, HbP, nullptr);
    mgemm<0,4><<<4*rb, 256, 0, stream>>>(HbP, 256, wb + WB_BB1H, wb + WB_BB1L, 512, 512,
                                         nullptr, SbC, nullptr, nullptr, nullptr);
    scan_k<false><<<CB*4, 64, 0, stream>>>(SbC, pr+256, pr+768, xlr + b0*256, xli + b0*256);
    ylast_k<<<CB, 256, 0, stream>>>(xlr + b0*256, xli + b0*256, Cssm + 2*65536, Dssm + 256,
                                    HbP, Xf, b0, ylr);
  }

  tail_k<<<BSZ, 256, 0, stream>>>(ylr, ln_g + 256, ln_b + 256, W1 + 65536, b1 + 256,
                                  W2 + 65536, b2 + 256, lnfg, lnfb, seqs, xfin);
  logits_k<<<(BSZ*NCAND + 3)/4, 256, 0, stream>>>(xfin, cand, iemb, (float*)d_out);
}

// Round 3
// 2227.285 us; speedup vs baseline: 1.1909x; 1.1909x over previous
//
#include <hip/hip_runtime.h>
#include <hip/hip_bf16.h>

// ---------------- problem constants ----------------
#define BSZ 64
#define SEQ 2048
#define HD  256
#define ND  256
#define BS_TOK (BSZ*SEQ)          // 131072 tokens
#define NCAND 101
#define EPS 1e-5f

using bf16 = __hip_bfloat16;
typedef unsigned short u16;
typedef unsigned int   u32;
typedef __attribute__((ext_vector_type(8))) short short8v;   // 8 bf16 (4 VGPRs)
typedef __attribute__((ext_vector_type(4))) float f32x4;

__device__ __forceinline__ float clampf(float v, float c) { return fminf(fmaxf(v, -c), c); }

// fp32 -> (hi,lo) bf16 split: x ~= hi + lo exactly to ~2^-17 rel
__device__ __forceinline__ void split_bf(float x, u16& h, u16& l) {
  u32 u = __float_as_uint(x);
  h = (u16)(u >> 16);
  float d = x - __uint_as_float(u & 0xffff0000u);
  l = (u16)(__float_as_uint(d) >> 16);
}
__device__ __forceinline__ u32 pack_pair(float x) {
  u16 h, l; split_bf(x, h, l);
  return (u32)h | ((u32)l << 16);
}
__device__ __forceinline__ float unpack_pair(u32 p) {
  return __uint_as_float(p << 16) + __uint_as_float(p & 0xffff0000u);
}

// async 16B global->LDS (wave-uniform LDS base + lane*16)
__device__ __forceinline__ void async_copy16(const void* g, void* l) {
  __builtin_amdgcn_global_load_lds(
      (const __attribute__((address_space(1))) void*)g,
      (__attribute__((address_space(3))) void*)l, 16, 0, 0);
}

// virtual-k pair swizzle: element (row r, logical u32 col c) stored at
//   row*ld + (c&~31) + ((((c>>2)&7) ^ (r&7))<<2) + (c&3)
__device__ __forceinline__ int vswz(int c, int rb7) {
  return (c & ~31) + ((((c >> 2) & 7) ^ rb7) << 2) + (c & 3);
}

// ---------------- workspace layout ----------------
static constexpr size_t MiB = 1024*1024;
static constexpr size_t OFF_X    = 0;                         // Xf fp32 [BS_TOK,256]
static constexpr size_t OFF_PR   = 128*MiB;                   // fp32[1024]: abr[512] abi[512]
static constexpr size_t OFF_WB   = OFF_PR + 4096;             // u16 4 MiB virt planes
static constexpr size_t OFF_XLR  = OFF_WB + 4*MiB;
static constexpr size_t OFF_XLI  = OFF_XLR + 65536;
static constexpr size_t OFF_YL   = OFF_XLI + 65536;
static constexpr size_t OFF_XF   = OFF_YL  + 65536;
static constexpr size_t OFF_CH   = 136*MiB;                   // Hb pairs 2*CB MiB, Sb 4*CB MiB

// wb u16 offsets (virtual-K duplicated planes, k-major per output col)
static constexpr int WB_BB0H = 0,       WB_BB0L = 262144;     // [512][Kv=512]
static constexpr int WB_BB1H = 524288,  WB_BB1L = 786432;
static constexpr int WB_WSH  = 1048576, WB_WSL  = 1310720;    // [256][Kv=1024]
static constexpr int WB_W1H  = 1572864, WB_W1L  = 1703936;    // [256][Kv=512]
static constexpr int WB_W2H  = 1835008, WB_W2L  = 1966080;

// ---------------- param pack ----------------
__global__ __launch_bounds__(256) void pack_k(
    const float* __restrict__ lar, const float* __restrict__ aim, const float* __restrict__ lstep,
    const float* __restrict__ C0, const float* __restrict__ W1, const float* __restrict__ W2,
    const float* __restrict__ Bf,
    float* __restrict__ pr, u16* __restrict__ wb)
{
  int gid = blockIdx.x*256 + threadIdx.x;   // grid 256 -> 65536
  if (gid < 512) {
    int blk = gid >> 8;
    float step = expf(clampf(lstep[blk], 10.f));
    float ar = -expf(clampf(lar[gid], 20.f));
    float ai = aim[gid];
    float er = expf(fminf(ar*step, 0.f));
    pr[gid]       = er * cosf(ai*step);
    pr[512 + gid] = er * sinf(ai*step);
  }
  int r = gid >> 8, c = gid & 255;          // r = n (state)/out col, c = h (hidden)/k
  u16 h, l;
#pragma unroll
  for (int blk = 0; blk < 2; ++blk) {
    float step = expf(clampf(lstep[blk], 10.f));
    float ar = -expf(clampf(lar[blk*256 + c], 20.f));
    float ai = aim[blk*256 + c];
    float er  = expf(fminf(ar*step, 0.f));
    float abr = er * cosf(ai*step);
    float abi = er * sinf(ai*step);
    float den = ar*ar + ai*ai;
    float tr = abr - 1.f, ti = abi;
    float cr = (tr*ar + ti*ai) / den;
    float ci = (ti*ar - tr*ai) / den;
    float bv = Bf[blk*65536 + r*256 + c];
    u16* Bh = wb + (blk ? WB_BB1H : WB_BB0H);
    u16* Bl = wb + (blk ? WB_BB1L : WB_BB0L);
    split_bf(cr * bv, h, l);
    Bh[r*512 + 2*c] = h; Bh[r*512 + 2*c + 1] = h;
    Bl[r*512 + 2*c] = l; Bl[r*512 + 2*c + 1] = l;
    split_bf(ci * bv, h, l);
    Bh[(256+r)*512 + 2*c] = h; Bh[(256+r)*512 + 2*c + 1] = h;
    Bl[(256+r)*512 + 2*c] = l; Bl[(256+r)*512 + 2*c + 1] = l;
  }
  // Wstk virt: out col = h (r), k = [n | 256+n] -> Kv=1024
  split_bf( C0[(size_t)(r*256 + c)*2    ], h, l);
  wb[WB_WSH + r*1024 + 2*c] = h; wb[WB_WSH + r*1024 + 2*c + 1] = h;
  wb[WB_WSL + r*1024 + 2*c] = l; wb[WB_WSL + r*1024 + 2*c + 1] = l;
  split_bf(-C0[(size_t)(r*256 + c)*2 + 1], h, l);
  wb[WB_WSH + r*1024 + 512 + 2*c] = h; wb[WB_WSH + r*1024 + 512 + 2*c + 1] = h;
  wb[WB_WSL + r*1024 + 512 + 2*c] = l; wb[WB_WSL + r*1024 + 512 + 2*c + 1] = l;
  // W1T/W2T virt: out col = n (r), k = c
  split_bf(W1[c*256 + r], h, l);
  wb[WB_W1H + r*512 + 2*c] = h; wb[WB_W1H + r*512 + 2*c + 1] = h;
  wb[WB_W1L + r*512 + 2*c] = l; wb[WB_W1L + r*512 + 2*c + 1] = l;
  split_bf(W2[c*256 + r], h, l);
  wb[WB_W2H + r*512 + 2*c] = h; wb[WB_W2H + r*512 + 2*c + 1] = h;
  wb[WB_W2L + r*512 + 2*c] = l; wb[WB_W2L + r*512 + 2*c + 1] = l;
}

// ---------------- fused embed + first LayerNorm (+ D*u residual) ----------------
// 1 wave per row. x = mask ? iemb[id]+pemb[pos] : 0; u = LN(x); Xf = x + D*u; OutP = pairs(u).
__global__ __launch_bounds__(256) void ln_emb_k(
    const int* __restrict__ seqs, const float* __restrict__ iemb,
    const float* __restrict__ pemb,
    const float* __restrict__ g, const float* __restrict__ b,
    float* __restrict__ Xf, u32* __restrict__ OutP, const float* __restrict__ Dv)
{
  int w = threadIdx.x >> 6, lane = threadIdx.x & 63;
  size_t row = (size_t)blockIdx.x * 4 + w;
  int id = seqs[row];
  int pos = (int)(row & (SEQ-1));
  float x[4] = {0.f, 0.f, 0.f, 0.f};
  if (id != 0) {
    float4 ev = ((const float4*)(iemb + (size_t)id*HD))[lane];
    float4 pv = ((const float4*)(pemb + (size_t)pos*HD))[lane];
    x[0] = ev.x + pv.x; x[1] = ev.y + pv.y; x[2] = ev.z + pv.z; x[3] = ev.w + pv.w;
  }
  float s = 0.f, s2 = 0.f;
#pragma unroll
  for (int k = 0; k < 4; ++k) { s += x[k]; s2 += x[k]*x[k]; }
#pragma unroll
  for (int off = 32; off > 0; off >>= 1) { s += __shfl_xor(s, off, 64); s2 += __shfl_xor(s2, off, 64); }
  float m = s * (1.f/256.f);
  float var = fmaxf(s2 * (1.f/256.f) - m*m, 0.f);
  float rinv = rsqrtf(var + EPS);
  int c0 = lane*4;
  u32 pv2[4]; float nx[4];
#pragma unroll
  for (int k = 0; k < 4; ++k) {
    float u = (x[k] - m) * rinv * g[c0+k] + b[c0+k];
    pv2[k] = pack_pair(u);
    nx[k] = x[k] + Dv[c0+k] * u;
  }
  int rb7 = (int)(row & 7);
  size_t o = row*256 + ((lane >> 3) << 5) + (((lane & 7) ^ rb7) << 2);
  *(uint4*)(OutP + o) = make_uint4(pv2[0], pv2[1], pv2[2], pv2[3]);
  ((float4*)(Xf + row*HD))[lane] = make_float4(nx[0], nx[1], nx[2], nx[3]);
}

// ---------------- LayerNorm (1 wave per row) -> swizzled (h,l) pair output ----------------
__global__ __launch_bounds__(256) void ln_rows(
    float* __restrict__ Xf, const float* __restrict__ g, const float* __restrict__ b,
    u32* __restrict__ OutP)
{
  int w = threadIdx.x >> 6, lane = threadIdx.x & 63;
  size_t row = (size_t)blockIdx.x * 4 + w;
  float* xrow = Xf + row*HD;
  float4 xv = ((const float4*)xrow)[lane];
  float x[4] = {xv.x, xv.y, xv.z, xv.w};
  float s = 0.f, s2 = 0.f;
#pragma unroll
  for (int k = 0; k < 4; ++k) { s += x[k]; s2 += x[k]*x[k]; }
#pragma unroll
  for (int off = 32; off > 0; off >>= 1) { s += __shfl_xor(s, off, 64); s2 += __shfl_xor(s2, off, 64); }
  float m = s * (1.f/256.f);
  float var = fmaxf(s2 * (1.f/256.f) - m*m, 0.f);
  float rinv = rsqrtf(var + EPS);
  int c0 = lane*4;
  u32 pv[4];
#pragma unroll
  for (int k = 0; k < 4; ++k) {
    float u = (x[k] - m) * rinv * g[c0+k] + b[c0+k];
    pv[k] = pack_pair(u);
  }
  int rb7 = (int)(row & 7);
  size_t o = row*256 + ((lane >> 3) << 5) + (((lane & 7) ^ rb7) << 2);
  *(uint4*)(OutP + o) = make_uint4(pv[0], pv[1], pv[2], pv[3]);
}

// ---------------- virtual-K pair MFMA GEMM ----------------
// out[m,n] = sum_k A[m,k]*W[n,k]; A = swizzled (h,l) u32 pairs (virt-K = 2K),
// W = duplicated bf16 planes. Two MFMA passes = exact (h+l)(wh+wl).
// A staged via global_load_lds 16B (linear dest; swizzle baked into global layout).
// 128x128 tile, 4 waves 2x2, BK=128 virt. XCD-bijective block remap.
template<int EPI, int CB_N>
__global__ __launch_bounds__(256) void mgemm(
    const u32* __restrict__ A, int ldau32,
    const u16* __restrict__ Bh, const u16* __restrict__ Bl, int Kv, int ldo,
    float* __restrict__ Xf, float* __restrict__ Of, u32* __restrict__ Op,
    const float* __restrict__ bias, const int* __restrict__ ids)
{
  __shared__ __align__(16) u16 As[128*128];   // 32 KiB
  const int tid  = threadIdx.x;
  const int lane = tid & 63, wid = tid >> 6;
  const int wr = wid >> 1, wc = wid & 1;
  const int l16 = lane & 15, lhi = lane >> 4;
  int g = blockIdx.x;
  int x = g & 7, j = g >> 3;
  int cb = j % CB_N, rbk = j / CB_N;
  const int m0 = (rbk*8 + x) * 128;
  const int n0 = cb*128 + wc*64;
  f32x4 acc[4][4] = {};
  const u16* A16 = (const u16*)A;
  const size_t lda16 = (size_t)ldau32 * 2;

  for (int kbv = 0; kbv < Kv; kbv += 128) {
    __syncthreads();
    // stage 128 rows x 128 u16 = 32 KiB: 2048 chunks of 16B, 8/thread
#pragma unroll
    for (int i = 0; i < 8; ++i) {
      int ch = (wid*8 + i)*64 + lane;               // 0..2047
      int rr = ch >> 4, grp = ch & 15;
      const u16* src = A16 + (size_t)(m0 + rr)*lda16 + kbv + grp*8;
      async_copy16(src, &As[(wid*8 + i)*512]);
    }
    __syncthreads();
#pragma unroll
    for (int kk = 0; kk < 128; kk += 32) {
      short8v af[4];
      const int c8 = (kk >> 3) + lhi;               // 0..15
      const int cw = c8 & ~7, cg = c8 & 7;
#pragma unroll
      for (int rf = 0; rf < 4; ++rf) {
        int r = wr*64 + rf*16 + l16;
        int off = r*128 + ((cw | (cg ^ (r & 7))) << 3);
        af[rf] = *(const short8v*)&As[off];
      }
#pragma unroll
      for (int nf = 0; nf < 4; ++nf) {
        size_t bo = (size_t)(n0 + nf*16 + l16)*Kv + kbv + kk + lhi*8;
        short8v bh = *(const short8v*)(Bh + bo);
        short8v bl = *(const short8v*)(Bl + bo);
#pragma unroll
        for (int rf = 0; rf < 4; ++rf) {
          f32x4 c = acc[rf][nf];
          c = __builtin_amdgcn_mfma_f32_16x16x32_bf16(af[rf], bh, c, 0, 0, 0);
          c = __builtin_amdgcn_mfma_f32_16x16x32_bf16(af[rf], bl, c, 0, 0, 0);
          acc[rf][nf] = c;
        }
      }
    }
  }
#pragma unroll
  for (int rf = 0; rf < 4; ++rf) {
#pragma unroll
    for (int jj = 0; jj < 4; ++jj) {
      int row = m0 + wr*64 + rf*16 + lhi*4 + jj;
      int rb7 = row & 7;
      int idv = 0;
      if (EPI == 3) idv = ids[row];
#pragma unroll
      for (int nf = 0; nf < 4; ++nf) {
        int col = n0 + nf*16 + l16;
        float v = acc[rf][nf][jj];
        if (EPI == 0) {
          Of[(size_t)row*ldo + col] = v;
        } else if (EPI == 2) {
          float t = fmaxf(v + bias[col], 0.f);
          Op[(size_t)row*ldo + vswz(col, rb7)] = pack_pair(t);
        } else if (EPI == 3) {
          size_t idx = (size_t)row*ldo + col;
          float t = Xf[idx] + v + bias[col];
          Xf[idx] = (idv != 0) ? t : 0.f;
        } else {
          size_t idx = (size_t)row*ldo + col;
          Xf[idx] = Xf[idx] + v;
        }
      }
    }
  }
}

// ---------------- 16-way time-parallel diagonal complex scan ----------------
// grid: CB*4 blocks (b = blk>>2, state-group = blk&3); block: 1024 thr = 16 waves.
// Wave w owns chunk t in [w*128, (w+1)*128).
// Phase 1: local scan from 0 (STORE: write local pairs in place, swizzled).
// Phase 2: s_w -> LDS; each wave combines carry E_{w-1} with A^128 (7 squarings).
// Phase 3 (STORE): correction pass x_t += A^{t_local+1} * E over own (L2-hot) chunk.
// !STORE: wave 15 emits final state E_15 only.
template<bool STORE>
__global__ __launch_bounds__(1024) void pscan_k(
    float* __restrict__ Sb,
    const float* __restrict__ arp, const float* __restrict__ aip,
    float* __restrict__ xlast_r, float* __restrict__ xlast_i)
{
  __shared__ float sR[16][64], sI[16][64];
  int lane = threadIdx.x & 63;
  int w = threadIdx.x >> 6;
  int b = blockIdx.x >> 2;
  int n = ((blockIdx.x & 3) << 6) | lane;
  float Ar = arp[n], Ai = aip[n];
  // A^128 by 7 squarings
  float p128r = Ar, p128i = Ai;
#pragma unroll
  for (int i = 0; i < 7; ++i) {
    float nr = p128r*p128r - p128i*p128i, ni = 2.f*p128r*p128i;
    p128r = nr; p128i = ni;
  }
  const int t0 = w*128;
  const float* sp = Sb + ((size_t)b*SEQ + t0)*512 + n;
  u32* qp = (u32*)Sb + (size_t)b*SEQ*512;
  int cr_base = (n & ~31) + (n & 3),   cr_g = (n >> 2) & 7;
  int ni2 = 256 + n;
  int ci_base = (ni2 & ~31) + (ni2 & 3), ci_g = (ni2 >> 2) & 7;

  // phase 1
  float xr = 0.f, xi = 0.f;
#pragma unroll 4
  for (int t = 0; t < 128; ++t) {
    float sr = sp[0], si = sp[256];
    float nxr = Ar*xr - Ai*xi + sr;
    float nxi = Ar*xi + Ai*xr + si;
    xr = nxr; xi = nxi;
    if (STORE) {
      int rb = (t0 + t) & 7;
      qp[(size_t)(t0 + t)*512 + cr_base + ((cr_g ^ rb) << 2)] = pack_pair(xr);
      qp[(size_t)(t0 + t)*512 + ci_base + ((ci_g ^ rb) << 2)] = pack_pair(xi);
    }
    sp += 512;
  }

  // phase 2
  sR[w][lane] = xr; sI[w][lane] = xi;
  __syncthreads();
  float er = 0.f, ei = 0.f;
  for (int q = 0; q < w; ++q) {
    float tr = p128r*er - p128i*ei + sR[q][lane];
    float ti = p128r*ei + p128i*er + sI[q][lane];
    er = tr; ei = ti;
  }

  if (!STORE) {
    if (w == 15) {
      float fr = p128r*er - p128i*ei + sR[15][lane];
      float fi = p128r*ei + p128i*er + sI[15][lane];
      xlast_r[b*ND + n] = fr; xlast_i[b*ND + n] = fi;
    }
    return;
  }

  // phase 3: x_t += A^{t+1} * E  (chunk 0 has E = 0)
  if (w == 0) return;
  float cr = Ar*er - Ai*ei, ci = Ar*ei + Ai*er;
#pragma unroll 4
  for (int t = 0; t < 128; ++t) {
    int tt = t0 + t; int rb = tt & 7;
    size_t orr = (size_t)tt*512 + cr_base + ((cr_g ^ rb) << 2);
    size_t oii = (size_t)tt*512 + ci_base + ((ci_g ^ rb) << 2);
    float vr = unpack_pair(qp[orr]) + cr;
    float vi = unpack_pair(qp[oii]) + ci;
    qp[orr] = pack_pair(vr);
    qp[oii] = pack_pair(vi);
    float nr = Ar*cr - Ai*ci, ni = Ar*ci + Ai*cr;
    cr = nr; ci = ni;
  }
}

// ---------------- block-1 last-position tail ----------------
__global__ __launch_bounds__(256) void ylast_k(
    const float* __restrict__ xr, const float* __restrict__ xi,
    const float* __restrict__ C1, const float* __restrict__ D1,
    const u32* __restrict__ U,                                  // chunk-local Hb pairs
    const float* __restrict__ Xf, int b0, float* __restrict__ ylr)
{
  int bl = blockIdx.x, h = threadIdx.x;
  __shared__ float sxr[256], sxi[256];
  sxr[h] = xr[bl*256 + h]; sxi[h] = xi[bl*256 + h];
  __syncthreads();
  float acc = 0.f;
  for (int n = 0; n < 256; ++n) {
    acc += C1[(size_t)(h*256 + n)*2] * sxr[n] - C1[(size_t)(h*256 + n)*2 + 1] * sxi[n];
  }
  size_t lrow = (size_t)bl*SEQ + SEQ - 1;     // last row; (row&7)==7
  u32 up = U[lrow*256 + vswz(h, 7)];
  float uval = unpack_pair(up);
  size_t gidx = ((size_t)(b0 + bl)*SEQ + SEQ - 1)*HD + h;
  ylr[(b0 + bl)*256 + h] = Xf[gidx] + acc + D1[h] * uval;
}

__device__ __forceinline__ float block_sum256(float v, volatile float* red) {
#pragma unroll
  for (int off = 32; off > 0; off >>= 1) v += __shfl_xor(v, off, 64);
  int w = threadIdx.x >> 6;
  __syncthreads();
  if ((threadIdx.x & 63) == 0) red[w] = v;
  __syncthreads();
  return red[0] + red[1] + red[2] + red[3];
}

__global__ __launch_bounds__(256) void tail_k(
    const float* __restrict__ ylr, const float* __restrict__ g1, const float* __restrict__ bb1,
    const float* __restrict__ W1p, const float* __restrict__ b1p,
    const float* __restrict__ W2p, const float* __restrict__ b2p,
    const float* __restrict__ fg, const float* __restrict__ fb,
    const int* __restrict__ seqs, float* __restrict__ xfin)
{
  __shared__ float sh[256];
  __shared__ float red[4];
  int b = blockIdx.x, h = threadIdx.x;
  float x = ylr[b*256 + h];
  float m = block_sum256(x, red) * (1.f/256.f);
  float d = x - m;
  float var = fmaxf(block_sum256(d*d, red) * (1.f/256.f), 0.f);
  float h2 = d * rsqrtf(var + EPS) * g1[h] + bb1[h];
  __syncthreads();
  sh[h] = h2;
  __syncthreads();
  float acc = 0.f;
  for (int k = 0; k < 256; ++k) acc += sh[k] * W1p[k*256 + h];
  float f = fmaxf(acc + b1p[h], 0.f);
  __syncthreads();
  sh[h] = f;
  __syncthreads();
  acc = 0.f;
  for (int k = 0; k < 256; ++k) acc += sh[k] * W2p[k*256 + h];
  float x2 = x + acc + b2p[h];
  if (seqs[b*SEQ + SEQ - 1] == 0) x2 = 0.f;
  float m2 = block_sum256(x2, red) * (1.f/256.f);
  float d2 = x2 - m2;
  float v2 = fmaxf(block_sum256(d2*d2, red) * (1.f/256.f), 0.f);
  xfin[b*256 + h] = d2 * rsqrtf(v2 + EPS) * fg[h] + fb[h];
}

// NOTE: reference output dtype is float32 -> d_out is float*.
__global__ __launch_bounds__(256) void logits_k(
    const float* __restrict__ xfin, const int* __restrict__ cand,
    const float* __restrict__ iemb, float* __restrict__ out)
{
  int gid = blockIdx.x*4 + (threadIdx.x >> 6);
  if (gid >= BSZ*NCAND) return;
  int lane = threadIdx.x & 63;
  int b = gid / NCAND;
  int id = cand[gid];
  const float* e  = iemb + (size_t)id*HD;
  const float* xv = xfin + b*256;
  float acc = 0.f;
#pragma unroll
  for (int k = 0; k < 4; ++k) acc += xv[lane*4 + k] * e[lane*4 + k];
#pragma unroll
  for (int off = 32; off > 0; off >>= 1) acc += __shfl_xor(acc, off, 64);
  if (lane == 0) out[gid] = acc;
}

// ---------------- launch ----------------
extern "C" void kernel_launch(void* const* d_in, const int* in_sizes, int n_in,
                              void* d_out, int out_size, void* d_ws, size_t ws_size,
                              hipStream_t stream)
{
  const int*   seqs  = (const int*)d_in[0];
  const int*   cand  = (const int*)d_in[1];
  const float* iemb  = (const float*)d_in[2];
  const float* pemb  = (const float*)d_in[3];
  const float* ln_g  = (const float*)d_in[4];
  const float* ln_b  = (const float*)d_in[5];
  const float* lar   = (const float*)d_in[6];
  const float* aim   = (const float*)d_in[7];
  const float* Bssm  = (const float*)d_in[8];
  const float* Cssm  = (const float*)d_in[9];
  const float* Dssm  = (const float*)d_in[10];
  const float* lstep = (const float*)d_in[11];
  const float* W1    = (const float*)d_in[12];
  const float* b1    = (const float*)d_in[13];
  const float* W2    = (const float*)d_in[14];
  const float* b2    = (const float*)d_in[15];
  const float* lnfg  = (const float*)d_in[16];
  const float* lnfb  = (const float*)d_in[17];

  char* ws = (char*)d_ws;
  float* Xf   = (float*)(ws + OFF_X);
  float* pr   = (float*)(ws + OFF_PR);
  u16*   wb   = (u16*)  (ws + OFF_WB);
  float* xlr  = (float*)(ws + OFF_XLR);
  float* xli  = (float*)(ws + OFF_XLI);
  float* ylr  = (float*)(ws + OFF_YL);
  float* xfin = (float*)(ws + OFF_XF);

  // chunk sizing: Hb pairs = 2*CB MiB, Sb = 4*CB MiB
  int CB = 64;
  while (CB > 1 && (OFF_CH + (size_t)6*CB*MiB) > ws_size) CB >>= 1;
  u32*   HbP = (u32*)(ws + OFF_CH);
  float* SbC = (float*)(ws + OFF_CH + (size_t)2*CB*MiB);

  pack_k<<<256, 256, 0, stream>>>(lar, aim, lstep, Cssm, W1, W2, Bssm, pr, wb);

  const int rows = CB*SEQ;
  const int rb   = rows / 128;
  for (int b0 = 0; b0 < BSZ; b0 += CB) {
    float* XfC = Xf + (size_t)b0*SEQ*HD;
    const int* seqC = seqs + (size_t)b0*SEQ;

    // ---- block 0: S4 ----
    ln_emb_k<<<rows/4, 256, 0, stream>>>(seqC, iemb, pemb, ln_g, ln_b, XfC, HbP, Dssm);
    mgemm<0,4><<<4*rb, 256, 0, stream>>>(HbP, 256, wb + WB_BB0H, wb + WB_BB0L, 512, 512,
                                         nullptr, SbC, nullptr, nullptr, nullptr);
    pscan_k<true><<<CB*4, 1024, 0, stream>>>(SbC, pr, pr+512, nullptr, nullptr);
    mgemm<4,2><<<2*rb, 256, 0, stream>>>((u32*)SbC, 512, wb + WB_WSH, wb + WB_WSL, 1024, 256,
                                         XfC, nullptr, nullptr, nullptr, nullptr);
    // ---- block 0: FFN ----
    ln_rows<<<rows/4, 256, 0, stream>>>(XfC, ln_g, ln_b, HbP);
    mgemm<2,2><<<2*rb, 256, 0, stream>>>(HbP, 256, wb + WB_W1H, wb + WB_W1L, 512, 256,
                                         nullptr, nullptr, (u32*)SbC, b1, nullptr);
    mgemm<3,2><<<2*rb, 256, 0, stream>>>((u32*)SbC, 256, wb + WB_W2H, wb + WB_W2L, 512, 256,
                                         XfC, nullptr, nullptr, b2, seqC);
    // ---- block 1 (only last position needed downstream of the scan) ----
    ln_rows<<<rows/4, 256, 0, stream>>>(XfC, ln_g + 256, ln_b + 256, HbP);
    mgemm<0,4><<<4*rb, 256, 0, stream>>>(HbP, 256, wb + WB_BB1H, wb + WB_BB1L, 512, 512,
                                         nullptr, SbC, nullptr, nullptr, nullptr);
    pscan_k<false><<<CB*4, 1024, 0, stream>>>(SbC, pr+256, pr+768, xlr + b0*256, xli + b0*256);
    ylast_k<<<CB, 256, 0, stream>>>(xlr + b0*256, xli + b0*256, Cssm + 2*65536, Dssm + 256,
                                    HbP, Xf, b0, ylr);
  }

  tail_k<<<BSZ, 256, 0, stream>>>(ylr, ln_g + 256, ln_b + 256, W1 + 65536, b1 + 256,
                                  W2 + 65536, b2 + 256, lnfg, lnfb, seqs, xfin);
  logits_k<<<(BSZ*NCAND + 3)/4, 256, 0, stream>>>(xfin, cand, iemb, (float*)d_out);
}

// Round 5
// 1706.045 us; speedup vs baseline: 1.5548x; 1.3055x over previous
//
#include <hip/hip_runtime.h>
#include <hip/hip_bf16.h>

// ---------------- problem constants ----------------
#define BSZ 64
#define SEQ 2048
#define HD  256
#define ND  256
#define BS_TOK (BSZ*SEQ)          // 131072 tokens
#define NCAND 101
#define EPS 1e-5f

using bf16 = __hip_bfloat16;
typedef unsigned short u16;
typedef unsigned int   u32;
typedef __attribute__((ext_vector_type(8))) short short8v;   // 8 bf16 (4 VGPRs)
typedef __attribute__((ext_vector_type(4))) float f32x4;

__device__ __forceinline__ float clampf(float v, float c) { return fminf(fmaxf(v, -c), c); }

// fp32 -> (hi,lo) bf16 split: x ~= hi + lo to ~2^-17 rel
__device__ __forceinline__ void split_bf(float x, u16& h, u16& l) {
  u32 u = __float_as_uint(x);
  h = (u16)(u >> 16);
  float d = x - __uint_as_float(u & 0xffff0000u);
  l = (u16)(__float_as_uint(d) >> 16);
}
__device__ __forceinline__ float comb_bf(u16 h, u16 l) {
  return __uint_as_float((u32)h << 16) + __uint_as_float((u32)l << 16);
}

// async 16B global->LDS (wave-uniform LDS base + lane*16)
__device__ __forceinline__ void async_copy16(const void* g, void* l) {
  __builtin_amdgcn_global_load_lds(
      (const __attribute__((address_space(1))) void*)g,
      (__attribute__((address_space(3))) void*)l, 16, 0, 0);
}

// Activation plane layout: per row of K logical cols, row stride = 2K u16.
// 64-col group gg occupies u16 [gg*128, gg*128+128): [hi 64 | lo 64],
// 8-u16 chunks XOR-swizzled by row&7 within each half.
// elem (row,k): hi at row*2K + (k>>6)*128 + (((k>>3)&7 ^ row&7)<<3) + (k&7); lo +64.

// ---------------- workspace layout ----------------
static constexpr size_t MiB = 1024*1024;
static constexpr size_t OFF_X    = 0;                         // Xf fp32 [BS_TOK,256]
static constexpr size_t OFF_PR   = 128*MiB;                   // fp32[1024]: abr[512] abi[512]
static constexpr size_t OFF_WB   = OFF_PR + 4096;             // u16 planes, 2 MiB used
static constexpr size_t OFF_XLR  = OFF_WB + 4*MiB;
static constexpr size_t OFF_XLI  = OFF_XLR + 65536;
static constexpr size_t OFF_YL   = OFF_XLI + 65536;
static constexpr size_t OFF_XF   = OFF_YL  + 65536;
static constexpr size_t OFF_CH   = 136*MiB;                   // Hb planes 2*CB MiB, Sb 4*CB MiB

// wb u16 offsets (hi/lo planes, k-major per output col, NOT duplicated)
static constexpr int WB_BB0H = 0,       WB_BB0L = 131072;     // [512 cols][K=256]
static constexpr int WB_BB1H = 262144,  WB_BB1L = 393216;
static constexpr int WB_WSH  = 524288,  WB_WSL  = 655360;     // [256 cols][K=512]
static constexpr int WB_W1H  = 786432,  WB_W1L  = 851968;     // [256 cols][K=256]
static constexpr int WB_W2H  = 917504,  WB_W2L  = 983040;

// ---------------- param pack ----------------
__global__ __launch_bounds__(256) void pack_k(
    const float* __restrict__ lar, const float* __restrict__ aim, const float* __restrict__ lstep,
    const float* __restrict__ C0, const float* __restrict__ W1, const float* __restrict__ W2,
    const float* __restrict__ Bf,
    float* __restrict__ pr, u16* __restrict__ wb)
{
  int gid = blockIdx.x*256 + threadIdx.x;   // grid 256 -> 65536
  if (gid < 512) {
    int blk = gid >> 8;
    float step = expf(clampf(lstep[blk], 10.f));
    float ar = -expf(clampf(lar[gid], 20.f));
    float ai = aim[gid];
    float er = expf(fminf(ar*step, 0.f));
    pr[gid]       = er * cosf(ai*step);
    pr[512 + gid] = er * sinf(ai*step);
  }
  int r = gid >> 8, c = gid & 255;          // r = out col (n or h), c = k index
  u16 h, l;
#pragma unroll
  for (int blk = 0; blk < 2; ++blk) {
    float step = expf(clampf(lstep[blk], 10.f));
    float ar = -expf(clampf(lar[blk*256 + c], 20.f));
    float ai = aim[blk*256 + c];
    float er  = expf(fminf(ar*step, 0.f));
    float abr = er * cosf(ai*step);
    float abi = er * sinf(ai*step);
    float den = ar*ar + ai*ai;
    float tr = abr - 1.f, ti = abi;
    float cr = (tr*ar + ti*ai) / den;
    float ci = (ti*ar - tr*ai) / den;
    float bv = Bf[blk*65536 + r*256 + c];
    u16* Bh = wb + (blk ? WB_BB1H : WB_BB0H);
    u16* Bl = wb + (blk ? WB_BB1L : WB_BB0L);
    split_bf(cr * bv, h, l); Bh[r*256 + c] = h;         Bl[r*256 + c] = l;
    split_bf(ci * bv, h, l); Bh[(256+r)*256 + c] = h;   Bl[(256+r)*256 + c] = l;
  }
  // Wstk: out col = h (r), k = [n | 256+n], K=512
  split_bf( C0[(size_t)(r*256 + c)*2    ], h, l);
  wb[WB_WSH + r*512 + c] = h;        wb[WB_WSL + r*512 + c] = l;
  split_bf(-C0[(size_t)(r*256 + c)*2 + 1], h, l);
  wb[WB_WSH + r*512 + 256 + c] = h;  wb[WB_WSL + r*512 + 256 + c] = l;
  // W1T/W2T: out col = n (r), k = c
  split_bf(W1[c*256 + r], h, l); wb[WB_W1H + r*256 + c] = h; wb[WB_W1L + r*256 + c] = l;
  split_bf(W2[c*256 + r], h, l); wb[WB_W2H + r*256 + c] = h; wb[WB_W2L + r*256 + c] = l;
}

// ---------------- plane-store helper for LN-type kernels ----------------
// writes 4 consecutive cols (c0 = lane*4) of one row into hi/lo planes
__device__ __forceinline__ void store4_planes(u16* rowp, int lane, int rb7,
                                              float a, float b, float c, float d) {
  int idx = ((lane >> 4) << 7) + (((((lane & 15) >> 1)) ^ rb7) << 3) + ((lane & 1) << 2);
  u16 h0,l0,h1,l1,h2,l2,h3,l3;
  split_bf(a, h0, l0); split_bf(b, h1, l1); split_bf(c, h2, l2); split_bf(d, h3, l3);
  *(uint2*)(rowp + idx)      = make_uint2((u32)h0 | ((u32)h1 << 16), (u32)h2 | ((u32)h3 << 16));
  *(uint2*)(rowp + idx + 64) = make_uint2((u32)l0 | ((u32)l1 << 16), (u32)l2 | ((u32)l3 << 16));
}

// ---------------- fused embed + first LayerNorm (+ D*u residual) ----------------
__global__ __launch_bounds__(256) void ln_emb_k(
    const int* __restrict__ seqs, const float* __restrict__ iemb,
    const float* __restrict__ pemb,
    const float* __restrict__ g, const float* __restrict__ b,
    float* __restrict__ Xf, u16* __restrict__ OutP, const float* __restrict__ Dv)
{
  int w = threadIdx.x >> 6, lane = threadIdx.x & 63;
  size_t row = (size_t)blockIdx.x * 4 + w;
  int id = seqs[row];
  int pos = (int)(row & (SEQ-1));
  float x[4] = {0.f, 0.f, 0.f, 0.f};
  if (id != 0) {
    float4 ev = ((const float4*)(iemb + (size_t)id*HD))[lane];
    float4 pv = ((const float4*)(pemb + (size_t)pos*HD))[lane];
    x[0] = ev.x + pv.x; x[1] = ev.y + pv.y; x[2] = ev.z + pv.z; x[3] = ev.w + pv.w;
  }
  float s = 0.f, s2 = 0.f;
#pragma unroll
  for (int k = 0; k < 4; ++k) { s += x[k]; s2 += x[k]*x[k]; }
#pragma unroll
  for (int off = 32; off > 0; off >>= 1) { s += __shfl_xor(s, off, 64); s2 += __shfl_xor(s2, off, 64); }
  float m = s * (1.f/256.f);
  float var = fmaxf(s2 * (1.f/256.f) - m*m, 0.f);
  float rinv = rsqrtf(var + EPS);
  int c0 = lane*4;
  float u[4], nx[4];
#pragma unroll
  for (int k = 0; k < 4; ++k) {
    u[k] = (x[k] - m) * rinv * g[c0+k] + b[c0+k];
    nx[k] = x[k] + Dv[c0+k] * u[k];
  }
  store4_planes(OutP + row*512, lane, (int)(row & 7), u[0], u[1], u[2], u[3]);
  ((float4*)(Xf + row*HD))[lane] = make_float4(nx[0], nx[1], nx[2], nx[3]);
}

// ---------------- LayerNorm (1 wave per row) -> plane output ----------------
__global__ __launch_bounds__(256) void ln_rows(
    float* __restrict__ Xf, const float* __restrict__ g, const float* __restrict__ b,
    u16* __restrict__ OutP)
{
  int w = threadIdx.x >> 6, lane = threadIdx.x & 63;
  size_t row = (size_t)blockIdx.x * 4 + w;
  float* xrow = Xf + row*HD;
  float4 xv = ((const float4*)xrow)[lane];
  float x[4] = {xv.x, xv.y, xv.z, xv.w};
  float s = 0.f, s2 = 0.f;
#pragma unroll
  for (int k = 0; k < 4; ++k) { s += x[k]; s2 += x[k]*x[k]; }
#pragma unroll
  for (int off = 32; off > 0; off >>= 1) { s += __shfl_xor(s, off, 64); s2 += __shfl_xor(s2, off, 64); }
  float m = s * (1.f/256.f);
  float var = fmaxf(s2 * (1.f/256.f) - m*m, 0.f);
  float rinv = rsqrtf(var + EPS);
  int c0 = lane*4;
  float u[4];
#pragma unroll
  for (int k = 0; k < 4; ++k) u[k] = (x[k] - m) * rinv * g[c0+k] + b[c0+k];
  store4_planes(OutP + row*512, lane, (int)(row & 7), u[0], u[1], u[2], u[3]);
}

// ---------------- 3-term split MFMA GEMM, double-buffered async staging ----------------
// out[m,n] = sum_k A[m,k]*W[n,k]; A = hi/lo u16 planes (layout above, row stride ldp),
// W = hi/lo planes k-major. Products: Al*Bh + Ah*Bl + Ah*Bh.
// 128x128 tile, 4 waves 2x2 of 64x64, BK=64, LDS 2x32 KiB double buffer.
// stage(k+1) issued before compute(k): DMA hides under MFMA (T3-minimal).
// EPI: 0 = Of[row*ldo+col] = v (fp32)
//      2 = Op planes = relu(v + bias[col])           (ldo = u16 row stride)
//      3 = Xf = (Xf + v + bias[col]) * mask(ids[row])
//      4 = Xf += v
template<int EPI, int CB_N>
__global__ __launch_bounds__(256) void mgemm(
    const u16* __restrict__ A, int ldp,
    const u16* __restrict__ Bh, const u16* __restrict__ Bl, int K, int ldo,
    float* __restrict__ Xf, float* __restrict__ Of, u16* __restrict__ Op,
    const float* __restrict__ bias, const int* __restrict__ ids)
{
  __shared__ __align__(16) u16 As[2][16384];    // 2 x 32 KiB: [row 0..127][hi 64 | lo 64]
  const int tid  = threadIdx.x;
  const int lane = tid & 63, wid = tid >> 6;
  const int wr = wid >> 1, wc = wid & 1;
  const int l16 = lane & 15, lhi = lane >> 4;
  // XCD-bijective remap: each XCD owns a fixed row-panel set, iterates cb within
  int g = blockIdx.x;
  int xx = g & 7, j = g >> 3;
  int cb = j % CB_N, rbk = j / CB_N;
  const int m0 = (rbk*8 + xx) * 128;
  const int n0 = cb*128 + wc*64;
  f32x4 acc[4][4] = {};

  auto stage = [&](int buf, int kb) {
    const int ggo = (kb >> 6) << 7;             // group offset in u16
#pragma unroll
    for (int i = 0; i < 8; ++i) {
      int q = wid*8 + i;                        // wave-call 0..31
      int ch = q*64 + lane;                     // chunk 0..2047
      int rr = ch >> 4, jj = ch & 15;
      const u16* src = A + (size_t)(m0 + rr)*ldp + ggo + jj*8;
      async_copy16(src, &As[buf][q*512]);
    }
  };

  stage(0, 0);
  __syncthreads();                              // drain: buf0 ready
  int cur = 0;
  for (int kb = 0; kb < K; kb += 64) {
    if (kb + 64 < K) stage(cur ^ 1, kb + 64);   // prefetch next tile under compute
#pragma unroll
    for (int kk = 0; kk < 64; kk += 32) {
      short8v ahf[4], alf[4];
      const int c8 = (kk >> 3) + lhi;           // 0..7
#pragma unroll
      for (int rf = 0; rf < 4; ++rf) {
        int r = wr*64 + rf*16 + l16;
        int off = r*128 + ((c8 ^ (r & 7)) << 3);
        ahf[rf] = *(const short8v*)&As[cur][off];
        alf[rf] = *(const short8v*)&As[cur][off + 64];
      }
#pragma unroll
      for (int nf = 0; nf < 4; ++nf) {
        size_t bo = (size_t)(n0 + nf*16 + l16)*K + kb + kk + lhi*8;
        short8v bh = *(const short8v*)(Bh + bo);
        short8v bl = *(const short8v*)(Bl + bo);
#pragma unroll
        for (int rf = 0; rf < 4; ++rf) {
          f32x4 c = acc[rf][nf];
          c = __builtin_amdgcn_mfma_f32_16x16x32_bf16(alf[rf], bh, c, 0, 0, 0);
          c = __builtin_amdgcn_mfma_f32_16x16x32_bf16(ahf[rf], bl, c, 0, 0, 0);
          c = __builtin_amdgcn_mfma_f32_16x16x32_bf16(ahf[rf], bh, c, 0, 0, 0);
          acc[rf][nf] = c;
        }
      }
    }
    __syncthreads();                            // drains next-tile DMA + frees cur buf
    cur ^= 1;
  }
#pragma unroll
  for (int rf = 0; rf < 4; ++rf) {
#pragma unroll
    for (int jj = 0; jj < 4; ++jj) {
      int row = m0 + wr*64 + rf*16 + lhi*4 + jj;
      int rb7 = row & 7;
      int idv = 0;
      if (EPI == 3) idv = ids[row];
#pragma unroll
      for (int nf = 0; nf < 4; ++nf) {
        int col = n0 + nf*16 + l16;
        float v = acc[rf][nf][jj];
        if (EPI == 0) {
          Of[(size_t)row*ldo + col] = v;
        } else if (EPI == 2) {
          float t = fmaxf(v + bias[col], 0.f);
          u16 hh, ll; split_bf(t, hh, ll);
          size_t base = (size_t)row*ldo + ((col >> 6) << 7)
                      + ((((col >> 3) & 7) ^ rb7) << 3) + (col & 7);
          Op[base] = hh; Op[base + 64] = ll;
        } else if (EPI == 3) {
          size_t idx = (size_t)row*ldo + col;
          float t = Xf[idx] + v + bias[col];
          Xf[idx] = (idv != 0) ? t : 0.f;
        } else {
          size_t idx = (size_t)row*ldo + col;
          Xf[idx] = Xf[idx] + v;
        }
      }
    }
  }
}

// ---------------- 16-way time-parallel diagonal complex scan ----------------
// grid: CB*4 (b = blk>>2, state-group sg = blk&3); block 1024 thr = 16 waves.
// Wave w owns t in [w*128, (w+1)*128). STORE: in-place fp32 -> hi/lo planes;
// plane slots of this block's cols lie exactly inside the fp32 bytes it reads -> race-free.
template<bool STORE>
__global__ __launch_bounds__(1024) void pscan_k(
    float* __restrict__ Sb,
    const float* __restrict__ arp, const float* __restrict__ aip,
    float* __restrict__ xlast_r, float* __restrict__ xlast_i)
{
  __shared__ float sR[16][64], sI[16][64];
  int lane = threadIdx.x & 63;
  int w = threadIdx.x >> 6;
  int b = blockIdx.x >> 2;
  int sg = blockIdx.x & 3;
  int n = (sg << 6) | lane;
  float Ar = arp[n], Ai = aip[n];
  float p128r = Ar, p128i = Ai;
#pragma unroll
  for (int i = 0; i < 7; ++i) {
    float nr = p128r*p128r - p128i*p128i, ni = 2.f*p128r*p128i;
    p128r = nr; p128i = ni;
  }
  const int t0 = w*128;
  const float* sp = Sb + ((size_t)b*SEQ + t0)*512 + n;
  u16* qp16 = (u16*)(Sb + (size_t)b*SEQ*512);
  const int sgo = sg << 7;                      // group base (u16): sg*128
  const int lo3 = lane & 7, lh3 = lane >> 3;

  // phase 1: local scan
  float xr = 0.f, xi = 0.f;
#pragma unroll 4
  for (int t = 0; t < 128; ++t) {
    float sr = sp[0], si = sp[256];
    float nxr = Ar*xr - Ai*xi + sr;
    float nxi = Ar*xi + Ai*xr + si;
    xr = nxr; xi = nxi;
    if (STORE) {
      int tt = t0 + t;
      size_t si2 = (size_t)tt*1024 + sgo + (((lh3 ^ (tt & 7))) << 3) + lo3;
      u16 hh, ll;
      split_bf(xr, hh, ll); qp16[si2] = hh;       qp16[si2 + 64]  = ll;
      split_bf(xi, hh, ll); qp16[si2 + 512] = hh; qp16[si2 + 576] = ll;
    }
    sp += 512;
  }

  // phase 2: carries
  sR[w][lane] = xr; sI[w][lane] = xi;
  __syncthreads();
  float er = 0.f, ei = 0.f;
  for (int q = 0; q < w; ++q) {
    float tr = p128r*er - p128i*ei + sR[q][lane];
    float ti = p128r*ei + p128i*er + sI[q][lane];
    er = tr; ei = ti;
  }

  if (!STORE) {
    if (w == 15) {
      float fr = p128r*er - p128i*ei + sR[15][lane];
      float fi = p128r*ei + p128i*er + sI[15][lane];
      xlast_r[b*ND + n] = fr; xlast_i[b*ND + n] = fi;
    }
    return;
  }

  // phase 3: x_t += A^{t+1} * E (chunk 0: E = 0)
  if (w == 0) return;
  float cr = Ar*er - Ai*ei, ci = Ar*ei + Ai*er;
#pragma unroll 4
  for (int t = 0; t < 128; ++t) {
    int tt = t0 + t;
    size_t si2 = (size_t)tt*1024 + sgo + (((lh3 ^ (tt & 7))) << 3) + lo3;
    float vr = comb_bf(qp16[si2],       qp16[si2 + 64])  + cr;
    float vi = comb_bf(qp16[si2 + 512], qp16[si2 + 576]) + ci;
    u16 hh, ll;
    split_bf(vr, hh, ll); qp16[si2] = hh;       qp16[si2 + 64]  = ll;
    split_bf(vi, hh, ll); qp16[si2 + 512] = hh; qp16[si2 + 576] = ll;
    float nr = Ar*cr - Ai*ci, ni = Ar*ci + Ai*cr;
    cr = nr; ci = ni;
  }
}

// ---------------- block-1 last-position tail ----------------
__global__ __launch_bounds__(256) void ylast_k(
    const float* __restrict__ xr, const float* __restrict__ xi,
    const float* __restrict__ C1, const float* __restrict__ D1,
    const u16* __restrict__ U,                                  // chunk-local Hb planes
    const float* __restrict__ Xf, int b0, float* __restrict__ ylr)
{
  int bl = blockIdx.x, h = threadIdx.x;
  __shared__ float sxr[256], sxi[256];
  sxr[h] = xr[bl*256 + h]; sxi[h] = xi[bl*256 + h];
  __syncthreads();
  float acc = 0.f;
  for (int n = 0; n < 256; ++n) {
    acc += C1[(size_t)(h*256 + n)*2] * sxr[n] - C1[(size_t)(h*256 + n)*2 + 1] * sxi[n];
  }
  size_t lrow = (size_t)bl*SEQ + SEQ - 1;     // (lrow&7)==7
  size_t ub = lrow*512 + ((h >> 6) << 7) + ((((h >> 3) & 7) ^ 7) << 3) + (h & 7);
  float uval = comb_bf(U[ub], U[ub + 64]);
  size_t gidx = ((size_t)(b0 + bl)*SEQ + SEQ - 1)*HD + h;
  ylr[(b0 + bl)*256 + h] = Xf[gidx] + acc + D1[h] * uval;
}

__device__ __forceinline__ float block_sum256(float v, volatile float* red) {
#pragma unroll
  for (int off = 32; off > 0; off >>= 1) v += __shfl_xor(v, off, 64);
  int w = threadIdx.x >> 6;
  __syncthreads();
  if ((threadIdx.x & 63) == 0) red[w] = v;
  __syncthreads();
  return red[0] + red[1] + red[2] + red[3];
}

__global__ __launch_bounds__(256) void tail_k(
    const float* __restrict__ ylr, const float* __restrict__ g1, const float* __restrict__ bb1,
    const float* __restrict__ W1p, const float* __restrict__ b1p,
    const float* __restrict__ W2p, const float* __restrict__ b2p,
    const float* __restrict__ fg, const float* __restrict__ fb,
    const int* __restrict__ seqs, float* __restrict__ xfin)
{
  __shared__ float sh[256];
  __shared__ float red[4];
  int b = blockIdx.x, h = threadIdx.x;
  float x = ylr[b*256 + h];
  float m = block_sum256(x, red) * (1.f/256.f);
  float d = x - m;
  float var = fmaxf(block_sum256(d*d, red) * (1.f/256.f), 0.f);
  float h2 = d * rsqrtf(var + EPS) * g1[h] + bb1[h];
  __syncthreads();
  sh[h] = h2;
  __syncthreads();
  float acc = 0.f;
  for (int k = 0; k < 256; ++k) acc += sh[k] * W1p[k*256 + h];
  float f = fmaxf(acc + b1p[h], 0.f);
  __syncthreads();
  sh[h] = f;
  __syncthreads();
  acc = 0.f;
  for (int k = 0; k < 256; ++k) acc += sh[k] * W2p[k*256 + h];
  float x2 = x + acc + b2p[h];
  if (seqs[b*SEQ + SEQ - 1] == 0) x2 = 0.f;
  float m2 = block_sum256(x2, red) * (1.f/256.f);
  float d2 = x2 - m2;
  float v2 = fmaxf(block_sum256(d2*d2, red) * (1.f/256.f), 0.f);
  xfin[b*256 + h] = d2 * rsqrtf(v2 + EPS) * fg[h] + fb[h];
}

// NOTE: reference output dtype is float32 -> d_out is float*.
__global__ __launch_bounds__(256) void logits_k(
    const float* __restrict__ xfin, const int* __restrict__ cand,
    const float* __restrict__ iemb, float* __restrict__ out)
{
  int gid = blockIdx.x*4 + (threadIdx.x >> 6);
  if (gid >= BSZ*NCAND) return;
  int lane = threadIdx.x & 63;
  int b = gid / NCAND;
  int id = cand[gid];
  const float* e  = iemb + (size_t)id*HD;
  const float* xv = xfin + b*256;
  float acc = 0.f;
#pragma unroll
  for (int k = 0; k < 4; ++k) acc += xv[lane*4 + k] * e[lane*4 + k];
#pragma unroll
  for (int off = 32; off > 0; off >>= 1) acc += __shfl_xor(acc, off, 64);
  if (lane == 0) out[gid] = acc;
}

// ---------------- launch ----------------
extern "C" void kernel_launch(void* const* d_in, const int* in_sizes, int n_in,
                              void* d_out, int out_size, void* d_ws, size_t ws_size,
                              hipStream_t stream)
{
  const int*   seqs  = (const int*)d_in[0];
  const int*   cand  = (const int*)d_in[1];
  const float* iemb  = (const float*)d_in[2];
  const float* pemb  = (const float*)d_in[3];
  const float* ln_g  = (const float*)d_in[4];
  const float* ln_b  = (const float*)d_in[5];
  const float* lar   = (const float*)d_in[6];
  const float* aim   = (const float*)d_in[7];
  const float* Bssm  = (const float*)d_in[8];
  const float* Cssm  = (const float*)d_in[9];
  const float* Dssm  = (const float*)d_in[10];
  const float* lstep = (const float*)d_in[11];
  const float* W1    = (const float*)d_in[12];
  const float* b1    = (const float*)d_in[13];
  const float* W2    = (const float*)d_in[14];
  const float* b2    = (const float*)d_in[15];
  const float* lnfg  = (const float*)d_in[16];
  const float* lnfb  = (const float*)d_in[17];

  char* ws = (char*)d_ws;
  float* Xf   = (float*)(ws + OFF_X);
  float* pr   = (float*)(ws + OFF_PR);
  u16*   wb   = (u16*)  (ws + OFF_WB);
  float* xlr  = (float*)(ws + OFF_XLR);
  float* xli  = (float*)(ws + OFF_XLI);
  float* ylr  = (float*)(ws + OFF_YL);
  float* xfin = (float*)(ws + OFF_XF);

  // chunk sizing: Hb planes = 2*CB MiB, Sb = 4*CB MiB
  int CB = 64;
  while (CB > 1 && (OFF_CH + (size_t)6*CB*MiB) > ws_size) CB >>= 1;
  u16*   HbP = (u16*)(ws + OFF_CH);
  float* SbC = (float*)(ws + OFF_CH + (size_t)2*CB*MiB);

  pack_k<<<256, 256, 0, stream>>>(lar, aim, lstep, Cssm, W1, W2, Bssm, pr, wb);

  const int rows = CB*SEQ;
  const int rb   = rows / 128;
  for (int b0 = 0; b0 < BSZ; b0 += CB) {
    float* XfC = Xf + (size_t)b0*SEQ*HD;
    const int* seqC = seqs + (size_t)b0*SEQ;

    // ---- block 0: S4 ----
    ln_emb_k<<<rows/4, 256, 0, stream>>>(seqC, iemb, pemb, ln_g, ln_b, XfC, HbP, Dssm);
    mgemm<0,4><<<4*rb, 256, 0, stream>>>(HbP, 512, wb + WB_BB0H, wb + WB_BB0L, 256, 512,
                                         nullptr, SbC, nullptr, nullptr, nullptr);
    pscan_k<true><<<CB*4, 1024, 0, stream>>>(SbC, pr, pr+512, nullptr, nullptr);
    mgemm<4,2><<<2*rb, 256, 0, stream>>>((u16*)SbC, 1024, wb + WB_WSH, wb + WB_WSL, 512, 256,
                                         XfC, nullptr, nullptr, nullptr, nullptr);
    // ---- block 0: FFN ----
    ln_rows<<<rows/4, 256, 0, stream>>>(XfC, ln_g, ln_b, HbP);
    mgemm<2,2><<<2*rb, 256, 0, stream>>>(HbP, 512, wb + WB_W1H, wb + WB_W1L, 256, 512,
                                         nullptr, nullptr, (u16*)SbC, b1, nullptr);
    mgemm<3,2><<<2*rb, 256, 0, stream>>>((u16*)SbC, 512, wb + WB_W2H, wb + WB_W2L, 256, 256,
                                         XfC, nullptr, nullptr, b2, seqC);
    // ---- block 1 (only last position needed downstream of the scan) ----
    ln_rows<<<rows/4, 256, 0, stream>>>(XfC, ln_g + 256, ln_b + 256, HbP);
    mgemm<0,4><<<4*rb, 256, 0, stream>>>(HbP, 512, wb + WB_BB1H, wb + WB_BB1L, 256, 512,
                                         nullptr, SbC, nullptr, nullptr, nullptr);
    pscan_k<false><<<CB*4, 1024, 0, stream>>>(SbC, pr+256, pr+768, xlr + b0*256, xli + b0*256);
    ylast_k<<<CB, 256, 0, stream>>>(xlr + b0*256, xli + b0*256, Cssm + 2*65536, Dssm + 256,
                                    HbP, Xf, b0, ylr);
  }

  tail_k<<<BSZ, 256, 0, stream>>>(ylr, ln_g + 256, ln_b + 256, W1 + 65536, b1 + 256,
                                  W2 + 65536, b2 + 256, lnfg, lnfb, seqs, xfin);
  logits_k<<<(BSZ*NCAND + 3)/4, 256, 0, stream>>>(xfin, cand, iemb, (float*)d_out);
}